// Round 1
// baseline (102.370 us; speedup 1.0000x reference)
//
#include <hip/hip_runtime.h>

// Problem: x (B=16, C=256, N=4096) fp32.
//   m[b,c]    = mean_n x[b,c,n]
//   score[b,n]= sum_c x[b,c,n] * m[b,c]
//   out[b,n]  = sigmoid(score[b,n])   -> (B,1,1,N) fp32, out_size = 65536
//
// Memory-bound: two passes over x (128 MiB) is the structural minimum.

#define B_DIM 16
#define C_DIM 256
#define N_DIM 4096

// ---------------- Kernel 1: row means -> ws ----------------
// One 256-thread block per row (b*C + c). 4096 floats/row = 1024 float4,
// 4 float4 per thread.
__global__ __launch_bounds__(256) void mean_rows_kernel(
    const float* __restrict__ x, float* __restrict__ m) {
  const int row = blockIdx.x;
  const float4* xr =
      reinterpret_cast<const float4*>(x + (size_t)row * N_DIM);
  float s = 0.0f;
#pragma unroll
  for (int i = 0; i < 4; ++i) {
    float4 v = xr[threadIdx.x + i * 256];
    s += (v.x + v.y) + (v.z + v.w);
  }
  // wave-64 shuffle reduce
#pragma unroll
  for (int off = 32; off > 0; off >>= 1) s += __shfl_down(s, off, 64);
  __shared__ float wsum[4];
  const int lane = threadIdx.x & 63;
  const int wid = threadIdx.x >> 6;
  if (lane == 0) wsum[wid] = s;
  __syncthreads();
  if (threadIdx.x == 0) {
    float t = (wsum[0] + wsum[1]) + (wsum[2] + wsum[3]);
    m[row] = t * (1.0f / (float)N_DIM);
  }
}

// ---------------- Kernel 2: scores + sigmoid ----------------
// grid = B * (N/256) = 256 blocks, 256 threads; thread -> one n.
// Lane-contiguous n => coalesced 256B/wave loads. m[b,:] staged in LDS
// (uniform read per iter -> broadcast, no bank conflict).
__global__ __launch_bounds__(256) void score_kernel(
    const float* __restrict__ x, const float* __restrict__ m,
    float* __restrict__ out) {
  const int nblocks_per_b = N_DIM / 256;  // 16
  const int b = blockIdx.x / nblocks_per_b;
  const int nblk = blockIdx.x % nblocks_per_b;
  const int n = nblk * 256 + threadIdx.x;

  __shared__ float ms[C_DIM];
  ms[threadIdx.x] = m[b * C_DIM + threadIdx.x];
  __syncthreads();

  const float* xb = x + (size_t)b * C_DIM * N_DIM + n;
  float s = 0.0f;
#pragma unroll 8
  for (int c = 0; c < C_DIM; ++c) {
    s += xb[(size_t)c * N_DIM] * ms[c];
  }
  out[(size_t)b * N_DIM + n] = 1.0f / (1.0f + expf(-s));
}

extern "C" void kernel_launch(void* const* d_in, const int* in_sizes, int n_in,
                              void* d_out, int out_size, void* d_ws,
                              size_t ws_size, hipStream_t stream) {
  const float* x = (const float*)d_in[0];
  float* out = (float*)d_out;
  float* m = (float*)d_ws;  // B*C = 4096 floats = 16 KiB

  mean_rows_kernel<<<B_DIM * C_DIM, 256, 0, stream>>>(x, m);
  score_kernel<<<B_DIM * (N_DIM / 256), 256, 0, stream>>>(x, m, out);
}

// Round 2
// 99.909 us; speedup vs baseline: 1.0246x; 1.0246x over previous
//
#include <hip/hip_runtime.h>

// Problem: x (B=16, C=256, N=4096) fp32.
//   m[b,c]     = mean_n x[b,c,n]
//   score[b,n] = sum_c x[b,c,n] * m[b,c]
//   out[b,n]   = sigmoid(score[b,n])  -> (B,1,1,N) fp32, out_size = 65536
//
// Memory-bound: two passes over x (2 x 64 MiB) is the structural minimum;
// second pass should be largely Infinity-Cache-served.

#define B_DIM 16
#define C_DIM 256
#define N_DIM 4096
#define CSPLIT 16                 // c-reduction split factor for kernel 2
#define CCHUNK (C_DIM / CSPLIT)   // 16 c's per block
#define NTILE 1024                // n's per block in kernel 2 (256 thr x float4)

// ---------------- Kernel 1: row means -> ws ----------------
// One 256-thread block per row (b*C + c). 4096 floats = 1024 float4.
__global__ __launch_bounds__(256) void mean_rows_kernel(
    const float* __restrict__ x, float* __restrict__ m) {
  const int row = blockIdx.x;
  const float4* xr = reinterpret_cast<const float4*>(x + (size_t)row * N_DIM);
  float s = 0.0f;
#pragma unroll
  for (int i = 0; i < 4; ++i) {
    float4 v = xr[threadIdx.x + i * 256];
    s += (v.x + v.y) + (v.z + v.w);
  }
#pragma unroll
  for (int off = 32; off > 0; off >>= 1) s += __shfl_down(s, off, 64);
  __shared__ float wsum[4];
  const int lane = threadIdx.x & 63;
  const int wid = threadIdx.x >> 6;
  if (lane == 0) wsum[wid] = s;
  __syncthreads();
  if (threadIdx.x == 0) {
    float t = (wsum[0] + wsum[1]) + (wsum[2] + wsum[3]);
    m[row] = t * (1.0f / (float)N_DIM);
  }
}

// ---------------- Kernel 2: partial scores ----------------
// grid = B * (N/NTILE) * CSPLIT = 16*4*16 = 1024 blocks, 256 threads.
// Block (b, nt, cs): n-range [nt*1024, nt*1024+1024), c-range
// [cs*16, cs*16+16). Each thread: one float4 of n, 16 independent
// float4 loads in flight. Partials -> ws.
__global__ __launch_bounds__(256) void partial_score_kernel(
    const float* __restrict__ x, const float* __restrict__ m,
    float* __restrict__ partials) {
  const int bid = blockIdx.x;
  const int cs = bid & (CSPLIT - 1);
  const int nt = (bid >> 4) & 3;
  const int b = bid >> 6;

  __shared__ float ms[CCHUNK];
  if (threadIdx.x < CCHUNK)
    ms[threadIdx.x] = m[b * C_DIM + cs * CCHUNK + threadIdx.x];
  __syncthreads();

  const int n0 = nt * NTILE + threadIdx.x * 4;
  const float* xb =
      x + (size_t)b * C_DIM * N_DIM + (size_t)(cs * CCHUNK) * N_DIM + n0;

  float4 acc = make_float4(0.f, 0.f, 0.f, 0.f);
#pragma unroll
  for (int c = 0; c < CCHUNK; ++c) {
    float4 v = *reinterpret_cast<const float4*>(xb + (size_t)c * N_DIM);
    float w = ms[c];
    acc.x += v.x * w;
    acc.y += v.y * w;
    acc.z += v.z * w;
    acc.w += v.w * w;
  }
  // layout: partials[cs][b][n]
  float* p = partials + ((size_t)cs * B_DIM + b) * N_DIM + n0;
  *reinterpret_cast<float4*>(p) = acc;
}

// ---------------- Kernel 3: reduce partials + sigmoid ----------------
// 65536 outputs / 4 per thread = 16384 threads = 64 blocks x 256.
__global__ __launch_bounds__(256) void reduce_sigmoid_kernel(
    const float* __restrict__ partials, float* __restrict__ out) {
  const int i4 = (blockIdx.x * 256 + threadIdx.x) * 4;  // flat b*N+n
  float4 s = make_float4(0.f, 0.f, 0.f, 0.f);
#pragma unroll
  for (int cs = 0; cs < CSPLIT; ++cs) {
    float4 v = *reinterpret_cast<const float4*>(
        partials + (size_t)cs * (B_DIM * N_DIM) + i4);
    s.x += v.x; s.y += v.y; s.z += v.z; s.w += v.w;
  }
  float4 o;
  o.x = 1.0f / (1.0f + __expf(-s.x));
  o.y = 1.0f / (1.0f + __expf(-s.y));
  o.z = 1.0f / (1.0f + __expf(-s.z));
  o.w = 1.0f / (1.0f + __expf(-s.w));
  *reinterpret_cast<float4*>(out + i4) = o;
}

extern "C" void kernel_launch(void* const* d_in, const int* in_sizes, int n_in,
                              void* d_out, int out_size, void* d_ws,
                              size_t ws_size, hipStream_t stream) {
  const float* x = (const float*)d_in[0];
  float* out = (float*)d_out;
  float* m = (float*)d_ws;                       // B*C floats = 16 KiB
  float* partials = (float*)d_ws + 4096;         // CSPLIT*B*N floats = 4 MiB

  mean_rows_kernel<<<B_DIM * C_DIM, 256, 0, stream>>>(x, m);
  partial_score_kernel<<<B_DIM * (N_DIM / NTILE) * CSPLIT, 256, 0, stream>>>(
      x, m, partials);
  reduce_sigmoid_kernel<<<(B_DIM * N_DIM) / 1024, 256, 0, stream>>>(partials,
                                                                    out);
}